// Round 9
// baseline (222.831 us; speedup 1.0000x reference)
//
#include <hip/hip_runtime.h>

#define TT 8192
#define CC 512

typedef unsigned short u16;
typedef unsigned int u32;
typedef __attribute__((ext_vector_type(8))) short bf16x8;
typedef __attribute__((ext_vector_type(4))) float f32x4;

#define VMCNT(N) asm volatile("s_waitcnt vmcnt(" #N ")" ::: "memory")
#define LGKM0()  asm volatile("s_waitcnt lgkmcnt(0)" ::: "memory")

__device__ __forceinline__ u16 f2bf(float f) {
    u32 u = __float_as_uint(f);
    return (u16)((u + 0x7FFFu + ((u >> 16) & 1u)) >> 16);
}

__device__ __forceinline__ void gld16(const u16* g, u16* l) {
    __builtin_amdgcn_global_load_lds(
        (const __attribute__((address_space(1))) u32*)g,
        (__attribute__((address_space(3))) u32*)l, 16, 0, 0);
}

// ---- Kernel 1: LN -> xx (bf16), out = x (residual pre-init), weight transposes ----
__global__ void lnw_kernel(const float* __restrict__ x,
                           const float* __restrict__ scale,
                           const float* __restrict__ bias,
                           const float* __restrict__ Wq,
                           const float* __restrict__ Wk,
                           const float* __restrict__ Wv,
                           u16* __restrict__ xx,
                           u16* __restrict__ wqkt,
                           u16* __restrict__ wvt,
                           float* __restrict__ out) {
    int b = blockIdx.x;
    if (b < 2048) {
        int row = b * 4 + (threadIdx.x >> 6);
        int l = threadIdx.x & 63;
        const float4* xr = (const float4*)(x + (size_t)row * CC);
        float4 a = xr[l * 2], c = xr[l * 2 + 1];
        float4* orow = (float4*)(out + (size_t)row * CC);
        orow[l * 2] = a;
        orow[l * 2 + 1] = c;
        float s = a.x + a.y + a.z + a.w + c.x + c.y + c.z + c.w;
        float q = a.x*a.x + a.y*a.y + a.z*a.z + a.w*a.w
                + c.x*c.x + c.y*c.y + c.z*c.z + c.w*c.w;
        #pragma unroll
        for (int m = 1; m < 64; m <<= 1) {
            s += __shfl_xor(s, m, 64);
            q += __shfl_xor(q, m, 64);
        }
        float mu = s * (1.0f / CC);
        float var = q * (1.0f / CC) - mu * mu;
        float rs = rsqrtf(var + 1e-5f);
        const float4* sc4 = (const float4*)scale;
        const float4* bi4 = (const float4*)bias;
        float4 s1 = sc4[l * 2], s2 = sc4[l * 2 + 1];
        float4 b1 = bi4[l * 2], b2 = bi4[l * 2 + 1];
        bf16x8 o;
        o[0] = (short)f2bf((a.x - mu) * rs * s1.x + b1.x);
        o[1] = (short)f2bf((a.y - mu) * rs * s1.y + b1.y);
        o[2] = (short)f2bf((a.z - mu) * rs * s1.z + b1.z);
        o[3] = (short)f2bf((a.w - mu) * rs * s1.w + b1.w);
        o[4] = (short)f2bf((c.x - mu) * rs * s2.x + b2.x);
        o[5] = (short)f2bf((c.y - mu) * rs * s2.y + b2.y);
        o[6] = (short)f2bf((c.z - mu) * rs * s2.z + b2.z);
        o[7] = (short)f2bf((c.w - mu) * rs * s2.w + b2.w);
        *(bf16x8*)(xx + (size_t)row * CC + l * 8) = o;
    } else {
        int tid = (b - 2048) * 256 + threadIdx.x;   // 0 .. 327679
        if (tid < 65536) {
            int c = tid >> 9, k = tid & 511;
            float w = (c < 64) ? Wq[k * 64 + c] : Wk[k * 64 + (c - 64)];
            wqkt[tid] = f2bf(w);
        } else {
            int i = tid - 65536;
            int c = i >> 9, k = i & 511;
            wvt[i] = f2bf(Wv[k * 512 + c]);
        }
    }
}

// ---------- Kernel 2: qk = xx @ [Wq|Wk], q scaled by 1/8 -> qk bf16 [T][128] ----------
__global__ __launch_bounds__(128) void qk_gemm_kernel(const u16* __restrict__ xx,
                                                      const u16* __restrict__ wqkt,
                                                      u16* __restrict__ qk) {
    int w = threadIdx.x >> 6;          // 0..1
    int l = threadIdx.x & 63;
    int l15 = l & 15, g = l >> 4;
    int r0 = blockIdx.x * 32 + w * 16;

    f32x4 acc[8];
    #pragma unroll
    for (int i = 0; i < 8; ++i) acc[i] = (f32x4){0.f, 0.f, 0.f, 0.f};

    for (int kk = 0; kk < 16; ++kk) {
        int k = kk * 32 + g * 8;
        bf16x8 af = *(const bf16x8*)(xx + (size_t)(r0 + l15) * CC + k);
        #pragma unroll
        for (int Nt = 0; Nt < 8; ++Nt) {
            int c = Nt * 16 + l15;
            bf16x8 bfr = *(const bf16x8*)(wqkt + c * CC + k);
            acc[Nt] = __builtin_amdgcn_mfma_f32_16x16x32_bf16(af, bfr, acc[Nt], 0, 0, 0);
        }
    }
    #pragma unroll
    for (int Nt = 0; Nt < 8; ++Nt) {
        int c = Nt * 16 + l15;
        float scl = (c < 64) ? 0.125f : 1.0f;
        #pragma unroll
        for (int jj = 0; jj < 4; ++jj) {
            int rg = r0 + g * 4 + jj;
            qk[rg * 128 + c] = f2bf(acc[Nt][jj] * scl);
        }
    }
}

// ---------- Kernel 3: vT = (x_emb @ Wv)^T -> vt bf16 [512][T], LDS-transposed store ----------
__global__ __launch_bounds__(256) void v_gemm_kernel(const float* __restrict__ xe,
                                                     const u16* __restrict__ wvt,
                                                     u16* __restrict__ vt) {
    __shared__ u16 tl[128 * 72];       // [c][r], row stride 72 (bank-spread)
    int w = threadIdx.x >> 6;
    int l = threadIdx.x & 63;
    int l15 = l & 15, g = l >> 4;
    int bm = blockIdx.x >> 2, bn = blockIdx.x & 3;
    int r0 = bm * 64 + w * 16;
    int c0 = bn * 128;

    f32x4 acc[8];
    #pragma unroll
    for (int i = 0; i < 8; ++i) acc[i] = (f32x4){0.f, 0.f, 0.f, 0.f};

    for (int kk = 0; kk < 16; ++kk) {
        int k = kk * 32 + g * 8;
        const float4* ap = (const float4*)(xe + (size_t)(r0 + l15) * CC + k);
        float4 a1 = ap[0], a2 = ap[1];
        bf16x8 af;
        af[0] = (short)f2bf(a1.x); af[1] = (short)f2bf(a1.y);
        af[2] = (short)f2bf(a1.z); af[3] = (short)f2bf(a1.w);
        af[4] = (short)f2bf(a2.x); af[5] = (short)f2bf(a2.y);
        af[6] = (short)f2bf(a2.z); af[7] = (short)f2bf(a2.w);
        #pragma unroll
        for (int Nt = 0; Nt < 8; ++Nt) {
            int c = c0 + Nt * 16 + l15;
            bf16x8 bfr = *(const bf16x8*)(wvt + c * CC + k);
            acc[Nt] = __builtin_amdgcn_mfma_f32_16x16x32_bf16(af, bfr, acc[Nt], 0, 0, 0);
        }
    }
    #pragma unroll
    for (int Nt = 0; Nt < 8; ++Nt) {
        int c = Nt * 16 + l15;                 // local col 0..127
        #pragma unroll
        for (int jj = 0; jj < 4; ++jj) {
            int r = w * 16 + g * 4 + jj;       // local row 0..63
            tl[c * 72 + r] = f2bf(acc[Nt][jj]);
        }
    }
    __syncthreads();
    int rb = bm * 64;
    #pragma unroll
    for (int i = 0; i < 4; ++i) {
        int chunk = i * 256 + threadIdx.x;     // 0..1023
        int c = chunk >> 3, r8 = chunk & 7;
        bf16x8 o = *(const bf16x8*)&tl[c * 72 + r8 * 8];
        *(bf16x8*)(vt + (size_t)(c0 + c) * TT + rb + r8 * 8) = o;
    }
}

// ---------- Kernel 4: flash, BM=128 x BN=256, 8 waves, 64KB LDS (2 blocks/CU) ----------
// V: reg-staged 1-iter-ahead (T14); K: gld16 DMA dbuf 2-ahead; counted vmcnt.
__global__ __launch_bounds__(512, 4) void flash_kernel(const u16* __restrict__ qk,
                                                       const u16* __restrict__ vt,
                                                       float* __restrict__ out,
                                                       int CT) {
    extern __shared__ u16 smem[];
    u16* const Klds = smem;            // 2 x [64 s][64 a] swizzled, 16KB
    u16* const Slds = smem + 8192;     // [128 r][64 s] swizzled, 16KB
    u16* const Vlds = smem + 16384;    // [256 c][64 s] swizzled, 32KB

    const int tid = threadIdx.x;
    const int w = tid >> 6, l = tid & 63;
    const int l15 = l & 15, g = l >> 4;
    const int wr = w >> 2, wcol = w & 3;     // PV: rows wr*64, cols wcol*64

    // decode blockIdx -> (rt, cb, ch); big-rt-first
    int b2 = (int)gridDim.x - 1 - (int)blockIdx.x;
    int rt = 0, base = 0;
    for (;;) {
        int nt_ = 2 * rt + 2, nc_ = (nt_ + CT - 1) / CT;
        if (b2 < base + 2 * nc_) break;
        base += 2 * nc_; ++rt;
    }
    const int rem = b2 - base;
    const int cb = rem & 1;
    const int ch = rem >> 1;
    const int nt = 2 * rt + 2, nc = (nt + CT - 1) / CT;
    const int t_lo = ch * nt / nc, t_hi = (ch + 1) * nt / nc;

    // Q fragments: wave w owns S rows [w*16, +16), pre-scaled by 1/8
    const int qrow = rt * 128 + w * 16 + l15;
    const bf16x8 qs0 = *(const bf16x8*)(qk + (size_t)qrow * 128 + g * 8);
    const bf16x8 qs1 = *(const bf16x8*)(qk + (size_t)qrow * 128 + 32 + g * 8);

    f32x4 acc[4][4];
    #pragma unroll
    for (int m = 0; m < 4; ++m)
        #pragma unroll
        for (int n = 0; n < 4; ++n) acc[m][n] = (f32x4){0.f, 0.f, 0.f, 0.f};

    // K DMA: 1 gld16/thread; linear dst row sIk slot pk, pre-swizzled source
    const int sIk = tid >> 3, pk = tid & 7;
    const int ka8 = (pk ^ (sIk & 7)) << 3;
    // V reg-stage: 4 bf16x8/thread
    const int vp = l & 7;
    const int vr0 = w * 8 + (l >> 3);          // local V row for i=0

    #define K_DMA(JT, PB) gld16(qk + (size_t)((JT) * 64 + sIk) * 128 + 64 + ka8, \
                                Klds + (PB) * 4096 + sIk * 64 + pk * 8)
    #define V_LOAD(JT, VREG) { \
        _Pragma("unroll") \
        for (int i = 0; i < 4; ++i) { \
            int c = i * 64 + vr0; \
            VREG[i] = *(const bf16x8*)(vt + (size_t)(cb * 256 + c) * TT + (JT) * 64 + ((vp ^ (c & 7)) << 3)); \
        } }
    #define V_WRITE(VREG) { \
        _Pragma("unroll") \
        for (int i = 0; i < 4; ++i) \
            *(bf16x8*)(Vlds + i * 4096 + w * 512 + l * 8) = VREG[i]; }

    bf16x8 vst[4];

    // prologue: K(t_lo) DMA -> buf0, V(t_lo) -> regs, K(t_lo+1) DMA -> buf1
    K_DMA(t_lo, 0);
    V_LOAD(t_lo, vst);
    if (t_lo + 1 < t_hi) { K_DMA(t_lo + 1, 1); VMCNT(1); } else { VMCNT(0); }
    V_WRITE(vst);
    LGKM0();
    __builtin_amdgcn_s_barrier();

    int pb = 0;
    for (int j = t_lo; j < t_hi; ++j) {
        const int s0 = j * 64;
        const bool more1 = (j + 1 < t_hi);
        const bool more2 = (j + 2 < t_hi);

        // A: issue V(j+1) -> regs (full iteration of latency)
        if (more1) V_LOAD(j + 1, vst);

        // B: QK^T from Klds[pb] (8 MFMA)
        const u16* Kb = Klds + pb * 4096;
        f32x4 sacc[4];
        #pragma unroll
        for (int Nt = 0; Nt < 4; ++Nt) sacc[Nt] = (f32x4){0.f, 0.f, 0.f, 0.f};
        #pragma unroll
        for (int Nt = 0; Nt < 4; ++Nt) {
            int srow = Nt * 16 + l15;
            #pragma unroll
            for (int ka = 0; ka < 2; ++ka) {
                int sl = (ka * 4 + g) ^ (srow & 7);
                bf16x8 kf = *(const bf16x8*)&Kb[srow * 64 + sl * 8];
                sacc[Nt] = __builtin_amdgcn_mfma_f32_16x16x32_bf16(
                    ka ? qs1 : qs0, kf, sacc[Nt], 0, 0, 0);
            }
        }

        // C: mask + cvt + S -> LDS (swizzled)
        const bool diag = (j >= 2 * rt);
        #pragma unroll
        for (int Nt = 0; Nt < 4; ++Nt) {
            int scol = Nt * 16 + l15;
            #pragma unroll
            for (int jj = 0; jj < 4; ++jj) {
                int row = w * 16 + g * 4 + jj;
                float val = sacc[Nt][jj];
                if (diag && (s0 + scol) > rt * 128 + row) val = 0.f;
                Slds[row * 64 + ((((scol >> 3) ^ (row & 7)) << 3) + (scol & 7))] = f2bf(val);
            }
        }
        LGKM0();
        __builtin_amdgcn_s_barrier();            // barrier1: S + V(j) visible

        // D: K(j+2) DMA into buf pb (QK^T(j) done reading it)
        if (more2) K_DMA(j + 2, pb);

        // E: PV (32 MFMA)
        __builtin_amdgcn_s_setprio(1);
        #pragma unroll
        for (int ka = 0; ka < 2; ++ka) {
            bf16x8 sf[4], vf[4];
            #pragma unroll
            for (int Mt = 0; Mt < 4; ++Mt) {
                int row = wr * 64 + Mt * 16 + l15;
                int sl = (ka * 4 + g) ^ (row & 7);
                sf[Mt] = *(const bf16x8*)&Slds[row * 64 + sl * 8];
            }
            #pragma unroll
            for (int Nt = 0; Nt < 4; ++Nt) {
                int cv = wcol * 64 + Nt * 16 + l15;
                int ph = (ka * 4 + g) ^ (cv & 7);
                vf[Nt] = *(const bf16x8*)&Vlds[cv * 64 + ph * 8];
            }
            #pragma unroll
            for (int Nt = 0; Nt < 4; ++Nt)
                #pragma unroll
                for (int Mt = 0; Mt < 4; ++Mt)
                    acc[Mt][Nt] = __builtin_amdgcn_mfma_f32_16x16x32_bf16(
                        sf[Mt], vf[Nt], acc[Mt][Nt], 0, 0, 0);
        }
        __builtin_amdgcn_s_setprio(0);

        // F: drain K(j+1) (published by barrier2); keep V(j+1) regs + K(j+2) in flight
        if (more2) { VMCNT(5); } else if (more1) { VMCNT(4); } else { VMCNT(0); }
        LGKM0();
        __builtin_amdgcn_s_barrier();            // barrier2: PV reads done, K(j+1) visible

        // G: V(j+1) regs -> LDS (buffer free; overlaps next QK^T)
        if (more1) {
            if (more2) { VMCNT(1); } else { VMCNT(0); }   // V(j+1) regs arrived
            V_WRITE(vst);
        }
        pb ^= 1;
    }

    // epilogue: atomic accumulate into out (pre-initialized to x by lnw)
    float* ob = out + (size_t)(rt * 128) * 512 + cb * 256;
    #pragma unroll
    for (int Mt = 0; Mt < 4; ++Mt) {
        #pragma unroll
        for (int Nt = 0; Nt < 4; ++Nt) {
            int col = wcol * 64 + Nt * 16 + l15;
            #pragma unroll
            for (int jj = 0; jj < 4; ++jj) {
                int row = wr * 64 + Mt * 16 + g * 4 + jj;
                atomicAdd(&ob[(size_t)row * 512 + col], acc[Mt][Nt][jj]);
            }
        }
    }
    #undef K_DMA
    #undef V_LOAD
    #undef V_WRITE
}

extern "C" void kernel_launch(void* const* d_in, const int* in_sizes, int n_in,
                              void* d_out, int out_size, void* d_ws, size_t ws_size,
                              hipStream_t stream) {
    (void)in_sizes; (void)n_in; (void)out_size; (void)ws_size;
    const float* x    = (const float*)d_in[0];
    const float* xe   = (const float*)d_in[1];
    const float* lns  = (const float*)d_in[2];
    const float* lnb  = (const float*)d_in[3];
    const float* Wq   = (const float*)d_in[4];
    const float* Wk   = (const float*)d_in[5];
    const float* Wv   = (const float*)d_in[6];
    float* out = (float*)d_out;
    char* ws = (char*)d_ws;

    size_t off_xx   = 0;                                   // bf16 [8192][512]  8 MB
    size_t off_qk   = off_xx   + (size_t)TT * CC * 2;      // bf16 [8192][128]  2 MB
    size_t off_wqkt = off_qk   + (size_t)TT * 128 * 2;     // bf16 [128][512]
    size_t off_wvt  = off_wqkt + (size_t)128 * 512 * 2;    // bf16 [512][512]
    size_t off_vt   = off_wvt  + (size_t)512 * 512 * 2;    // bf16 [512][8192]  8 MB

    // smallest CT with total blocks <= 512 (2 per CU)
    int CT = 2, slots = 0;
    for (;;) {
        slots = 0;
        for (int rt = 0; rt < 64; ++rt) slots += 2 * ((2 * rt + 2 + CT - 1) / CT);
        if (slots <= 512 || CT >= 256) break;
        ++CT;
    }

    u16* xx   = (u16*)(ws + off_xx);
    u16* qk   = (u16*)(ws + off_qk);
    u16* wqkt = (u16*)(ws + off_wqkt);
    u16* wvt  = (u16*)(ws + off_wvt);
    u16* vt   = (u16*)(ws + off_vt);

    const size_t flash_lds = (size_t)(8192 + 8192 + 16384) * sizeof(u16);  // 64 KB

    hipLaunchKernelGGL(lnw_kernel,     dim3(3328), dim3(256), 0, stream,
                       x, lns, lnb, Wq, Wk, Wv, xx, wqkt, wvt, out);
    hipLaunchKernelGGL(qk_gemm_kernel, dim3(256),  dim3(128), 0, stream, xx, wqkt, qk);
    hipLaunchKernelGGL(v_gemm_kernel,  dim3(512),  dim3(256), 0, stream, xe, wvt, vt);
    hipLaunchKernelGGL(flash_kernel,   dim3(slots), dim3(512), flash_lds, stream,
                       qk, vt, out, CT);
}

// Round 10
// 148.665 us; speedup vs baseline: 1.4989x; 1.4989x over previous
//
#include <hip/hip_runtime.h>

#define TT 8192
#define CC 512

typedef unsigned short u16;
typedef unsigned int u32;
typedef __attribute__((ext_vector_type(8))) short bf16x8;
typedef __attribute__((ext_vector_type(4))) float f32x4;

#define VMCNT0() asm volatile("s_waitcnt vmcnt(0)" ::: "memory")
#define LGKM0()  asm volatile("s_waitcnt lgkmcnt(0)" ::: "memory")

__device__ __forceinline__ u16 f2bf(float f) {
    u32 u = __float_as_uint(f);
    return (u16)((u + 0x7FFFu + ((u >> 16) & 1u)) >> 16);
}

__device__ __forceinline__ void gld16(const u16* g, u16* l) {
    __builtin_amdgcn_global_load_lds(
        (const __attribute__((address_space(1))) u32*)g,
        (__attribute__((address_space(3))) u32*)l, 16, 0, 0);
}

// ---- Kernel 1: LN -> xx (bf16), out = x (residual pre-init), weight transposes ----
__global__ void lnw_kernel(const float* __restrict__ x,
                           const float* __restrict__ scale,
                           const float* __restrict__ bias,
                           const float* __restrict__ Wq,
                           const float* __restrict__ Wk,
                           const float* __restrict__ Wv,
                           u16* __restrict__ xx,
                           u16* __restrict__ wqkt,
                           u16* __restrict__ wvt,
                           float* __restrict__ out) {
    int b = blockIdx.x;
    if (b < 2048) {
        int row = b * 4 + (threadIdx.x >> 6);
        int l = threadIdx.x & 63;
        const float4* xr = (const float4*)(x + (size_t)row * CC);
        float4 a = xr[l * 2], c = xr[l * 2 + 1];
        float4* orow = (float4*)(out + (size_t)row * CC);
        orow[l * 2] = a;
        orow[l * 2 + 1] = c;
        float s = a.x + a.y + a.z + a.w + c.x + c.y + c.z + c.w;
        float q = a.x*a.x + a.y*a.y + a.z*a.z + a.w*a.w
                + c.x*c.x + c.y*c.y + c.z*c.z + c.w*c.w;
        #pragma unroll
        for (int m = 1; m < 64; m <<= 1) {
            s += __shfl_xor(s, m, 64);
            q += __shfl_xor(q, m, 64);
        }
        float mu = s * (1.0f / CC);
        float var = q * (1.0f / CC) - mu * mu;
        float rs = rsqrtf(var + 1e-5f);
        const float4* sc4 = (const float4*)scale;
        const float4* bi4 = (const float4*)bias;
        float4 s1 = sc4[l * 2], s2 = sc4[l * 2 + 1];
        float4 b1 = bi4[l * 2], b2 = bi4[l * 2 + 1];
        bf16x8 o;
        o[0] = (short)f2bf((a.x - mu) * rs * s1.x + b1.x);
        o[1] = (short)f2bf((a.y - mu) * rs * s1.y + b1.y);
        o[2] = (short)f2bf((a.z - mu) * rs * s1.z + b1.z);
        o[3] = (short)f2bf((a.w - mu) * rs * s1.w + b1.w);
        o[4] = (short)f2bf((c.x - mu) * rs * s2.x + b2.x);
        o[5] = (short)f2bf((c.y - mu) * rs * s2.y + b2.y);
        o[6] = (short)f2bf((c.z - mu) * rs * s2.z + b2.z);
        o[7] = (short)f2bf((c.w - mu) * rs * s2.w + b2.w);
        *(bf16x8*)(xx + (size_t)row * CC + l * 8) = o;
    } else {
        int tid = (b - 2048) * 256 + threadIdx.x;   // 0 .. 327679
        if (tid < 65536) {
            int c = tid >> 9, k = tid & 511;
            float w = (c < 64) ? Wq[k * 64 + c] : Wk[k * 64 + (c - 64)];
            wqkt[tid] = f2bf(w);
        } else {
            int i = tid - 65536;
            int c = i >> 9, k = i & 511;
            wvt[i] = f2bf(Wv[k * 512 + c]);
        }
    }
}

// ---------- Kernel 2: qk = xx @ [Wq|Wk], q scaled by 1/8 -> qk bf16 [T][128] ----------
__global__ __launch_bounds__(128) void qk_gemm_kernel(const u16* __restrict__ xx,
                                                      const u16* __restrict__ wqkt,
                                                      u16* __restrict__ qk) {
    int w = threadIdx.x >> 6;          // 0..1
    int l = threadIdx.x & 63;
    int l15 = l & 15, g = l >> 4;
    int r0 = blockIdx.x * 32 + w * 16;

    f32x4 acc[8];
    #pragma unroll
    for (int i = 0; i < 8; ++i) acc[i] = (f32x4){0.f, 0.f, 0.f, 0.f};

    for (int kk = 0; kk < 16; ++kk) {
        int k = kk * 32 + g * 8;
        bf16x8 af = *(const bf16x8*)(xx + (size_t)(r0 + l15) * CC + k);
        #pragma unroll
        for (int Nt = 0; Nt < 8; ++Nt) {
            int c = Nt * 16 + l15;
            bf16x8 bfr = *(const bf16x8*)(wqkt + c * CC + k);
            acc[Nt] = __builtin_amdgcn_mfma_f32_16x16x32_bf16(af, bfr, acc[Nt], 0, 0, 0);
        }
    }
    #pragma unroll
    for (int Nt = 0; Nt < 8; ++Nt) {
        int c = Nt * 16 + l15;
        float scl = (c < 64) ? 0.125f : 1.0f;
        #pragma unroll
        for (int jj = 0; jj < 4; ++jj) {
            int rg = r0 + g * 4 + jj;
            qk[rg * 128 + c] = f2bf(acc[Nt][jj] * scl);
        }
    }
}

// ---------- Kernel 3: vT = (x_emb @ Wv)^T -> vt bf16 [512][T], LDS-transposed store ----------
__global__ __launch_bounds__(256) void v_gemm_kernel(const float* __restrict__ xe,
                                                     const u16* __restrict__ wvt,
                                                     u16* __restrict__ vt) {
    __shared__ u16 tl[128 * 72];       // [c][r], row stride 72 (bank-spread)
    int w = threadIdx.x >> 6;
    int l = threadIdx.x & 63;
    int l15 = l & 15, g = l >> 4;
    int bm = blockIdx.x >> 2, bn = blockIdx.x & 3;
    int r0 = bm * 64 + w * 16;
    int c0 = bn * 128;

    f32x4 acc[8];
    #pragma unroll
    for (int i = 0; i < 8; ++i) acc[i] = (f32x4){0.f, 0.f, 0.f, 0.f};

    for (int kk = 0; kk < 16; ++kk) {
        int k = kk * 32 + g * 8;
        const float4* ap = (const float4*)(xe + (size_t)(r0 + l15) * CC + k);
        float4 a1 = ap[0], a2 = ap[1];
        bf16x8 af;
        af[0] = (short)f2bf(a1.x); af[1] = (short)f2bf(a1.y);
        af[2] = (short)f2bf(a1.z); af[3] = (short)f2bf(a1.w);
        af[4] = (short)f2bf(a2.x); af[5] = (short)f2bf(a2.y);
        af[6] = (short)f2bf(a2.z); af[7] = (short)f2bf(a2.w);
        #pragma unroll
        for (int Nt = 0; Nt < 8; ++Nt) {
            int c = c0 + Nt * 16 + l15;
            bf16x8 bfr = *(const bf16x8*)(wvt + c * CC + k);
            acc[Nt] = __builtin_amdgcn_mfma_f32_16x16x32_bf16(af, bfr, acc[Nt], 0, 0, 0);
        }
    }
    #pragma unroll
    for (int Nt = 0; Nt < 8; ++Nt) {
        int c = Nt * 16 + l15;                 // local col 0..127
        #pragma unroll
        for (int jj = 0; jj < 4; ++jj) {
            int r = w * 16 + g * 4 + jj;       // local row 0..63
            tl[c * 72 + r] = f2bf(acc[Nt][jj]);
        }
    }
    __syncthreads();
    int rb = bm * 64;
    #pragma unroll
    for (int i = 0; i < 4; ++i) {
        int chunk = i * 256 + threadIdx.x;     // 0..1023
        int c = chunk >> 3, r8 = chunk & 7;
        bf16x8 o = *(const bf16x8*)&tl[c * 72 + r8 * 8];
        *(bf16x8*)(vt + (size_t)(c0 + c) * TT + rb + r8 * 8) = o;
    }
}

// ---------- Kernel 4: flash, BM=128 x BN=128, 8 waves, 64KB LDS (2 blocks/CU) ----------
// K and V both DMA double-buffered via global_load_lds; issue-after-barrier, full-iter span.
__global__ __launch_bounds__(512, 4) void flash_kernel(const u16* __restrict__ qk,
                                                       const u16* __restrict__ vt,
                                                       float* __restrict__ out,
                                                       int CT) {
    extern __shared__ u16 smem[];
    u16* const Klds = smem;            // 2 x [64 s][64 a] swizzled, 16KB
    u16* const Slds = smem + 8192;     // [128 r][64 s] swizzled, 16KB
    u16* const Vlds = smem + 16384;    // 2 x [128 c][64 s] swizzled, 32KB

    const int tid = threadIdx.x;
    const int w = tid >> 6, l = tid & 63;
    const int l15 = l & 15, g = l >> 4;
    const int wr = w >> 2, wcol = w & 3;     // PV: rows wr*64, cols wcol*32

    // decode blockIdx -> (rt, cb 0..3, ch); big-rt-first
    int b2 = (int)gridDim.x - 1 - (int)blockIdx.x;
    int rt = 0, base = 0;
    for (;;) {
        int nt_ = 2 * rt + 2, nc_ = (nt_ + CT - 1) / CT;
        if (b2 < base + 4 * nc_) break;
        base += 4 * nc_; ++rt;
    }
    const int rem = b2 - base;
    const int cb = rem & 3;
    const int ch = rem >> 2;
    const int nt = 2 * rt + 2, nc = (nt + CT - 1) / CT;
    const int t_lo = ch * nt / nc, t_hi = (ch + 1) * nt / nc;

    // Q fragments: wave w owns S rows [w*16, +16), pre-scaled by 1/8
    const int qrow = rt * 128 + w * 16 + l15;
    const bf16x8 qs0 = *(const bf16x8*)(qk + (size_t)qrow * 128 + g * 8);
    const bf16x8 qs1 = *(const bf16x8*)(qk + (size_t)qrow * 128 + 32 + g * 8);

    f32x4 acc[4][2];
    #pragma unroll
    for (int m = 0; m < 4; ++m)
        #pragma unroll
        for (int n = 0; n < 2; ++n) acc[m][n] = (f32x4){0.f, 0.f, 0.f, 0.f};

    // K DMA: 1 gld16/thread, linear dst tid*16, pre-swizzled source
    const int sIk = tid >> 3, pk = tid & 7;
    const int ka8 = (pk ^ (sIk & 7)) << 3;
    // V DMA: 2 gld16/thread; row c = i*64 + w*8 + (l>>3); c&7 == l>>3
    const int vr = w * 8 + (l >> 3);
    const int vsw = ((l & 7) ^ (l >> 3)) << 3;

    #define K_DMA(JT, B) gld16(qk + (size_t)((JT) * 64 + sIk) * 128 + 64 + ka8, \
                               Klds + (B) * 4096 + sIk * 64 + pk * 8)
    #define V_DMA(JT, B) { \
        _Pragma("unroll") \
        for (int i = 0; i < 2; ++i) { \
            int c = i * 64 + vr; \
            gld16(vt + (size_t)(cb * 128 + c) * TT + (JT) * 64 + vsw, \
                  Vlds + (B) * 8192 + c * 64 + (l & 7) * 8); \
        } }

    // prologue: DMA(t_lo) -> buf0
    V_DMA(t_lo, 0);
    K_DMA(t_lo, 0);

    int cur = 0;
    for (int j = t_lo; j < t_hi; ++j) {
        const int s0 = j * 64;
        const bool more = (j + 1 < t_hi);

        // 1: DMA(j) arrived (issued a full iter ago); prev PV ds-reads drained
        VMCNT0();
        LGKM0();
        __builtin_amdgcn_s_barrier();

        // 2: issue DMA(j+1) into the freed buffer; lands during compute below
        if (more) { V_DMA(j + 1, cur ^ 1); K_DMA(j + 1, cur ^ 1); }

        // 3: QK^T from K[cur] (8 MFMA): wave w rows [w*16,+16) x all 64 s
        const u16* Kb = Klds + cur * 4096;
        f32x4 sacc[4];
        #pragma unroll
        for (int Nt = 0; Nt < 4; ++Nt) sacc[Nt] = (f32x4){0.f, 0.f, 0.f, 0.f};
        __builtin_amdgcn_s_setprio(1);
        #pragma unroll
        for (int Nt = 0; Nt < 4; ++Nt) {
            int srow = Nt * 16 + l15;
            #pragma unroll
            for (int ka = 0; ka < 2; ++ka) {
                int sl = (ka * 4 + g) ^ (srow & 7);
                bf16x8 kf = *(const bf16x8*)&Kb[srow * 64 + sl * 8];
                sacc[Nt] = __builtin_amdgcn_mfma_f32_16x16x32_bf16(
                    ka ? qs1 : qs0, kf, sacc[Nt], 0, 0, 0);
            }
        }
        __builtin_amdgcn_s_setprio(0);

        // mask + cvt + S -> LDS (swizzled)
        const bool diag = (j >= 2 * rt);
        #pragma unroll
        for (int Nt = 0; Nt < 4; ++Nt) {
            int scol = Nt * 16 + l15;
            #pragma unroll
            for (int jj = 0; jj < 4; ++jj) {
                int row = w * 16 + g * 4 + jj;
                float val = sacc[Nt][jj];
                if (diag && (s0 + scol) > rt * 128 + row) val = 0.f;
                Slds[row * 64 + ((((scol >> 3) ^ (row & 7)) << 3) + (scol & 7))] = f2bf(val);
            }
        }

        // 4: S visible
        LGKM0();
        __builtin_amdgcn_s_barrier();

        // 5: PV from S + V[cur] (16 MFMA): rows [wr*64,+64) x cols [wcol*32,+32)
        const u16* Vb = Vlds + cur * 8192;
        __builtin_amdgcn_s_setprio(1);
        #pragma unroll
        for (int ka = 0; ka < 2; ++ka) {
            bf16x8 sf[4], vf[2];
            #pragma unroll
            for (int Mt = 0; Mt < 4; ++Mt) {
                int row = wr * 64 + Mt * 16 + l15;
                int sl = (ka * 4 + g) ^ (row & 7);
                sf[Mt] = *(const bf16x8*)&Slds[row * 64 + sl * 8];
            }
            #pragma unroll
            for (int Nt = 0; Nt < 2; ++Nt) {
                int cv = wcol * 32 + Nt * 16 + l15;
                int ph = (ka * 4 + g) ^ (cv & 7);
                vf[Nt] = *(const bf16x8*)&Vb[cv * 64 + ph * 8];
            }
            #pragma unroll
            for (int Nt = 0; Nt < 2; ++Nt)
                #pragma unroll
                for (int Mt = 0; Mt < 4; ++Mt)
                    acc[Mt][Nt] = __builtin_amdgcn_mfma_f32_16x16x32_bf16(
                        sf[Mt], vf[Nt], acc[Mt][Nt], 0, 0, 0);
        }
        __builtin_amdgcn_s_setprio(0);

        cur ^= 1;
    }

    // epilogue: atomic accumulate into out (pre-initialized to x by lnw)
    float* ob = out + (size_t)(rt * 128) * 512 + cb * 128;
    #pragma unroll
    for (int Mt = 0; Mt < 4; ++Mt) {
        #pragma unroll
        for (int Nt = 0; Nt < 2; ++Nt) {
            int col = wcol * 32 + Nt * 16 + l15;
            #pragma unroll
            for (int jj = 0; jj < 4; ++jj) {
                int row = wr * 64 + Mt * 16 + g * 4 + jj;
                atomicAdd(&ob[(size_t)row * 512 + col], acc[Mt][Nt][jj]);
            }
        }
    }
    #undef K_DMA
    #undef V_DMA
}

extern "C" void kernel_launch(void* const* d_in, const int* in_sizes, int n_in,
                              void* d_out, int out_size, void* d_ws, size_t ws_size,
                              hipStream_t stream) {
    (void)in_sizes; (void)n_in; (void)out_size; (void)ws_size;
    const float* x    = (const float*)d_in[0];
    const float* xe   = (const float*)d_in[1];
    const float* lns  = (const float*)d_in[2];
    const float* lnb  = (const float*)d_in[3];
    const float* Wq   = (const float*)d_in[4];
    const float* Wk   = (const float*)d_in[5];
    const float* Wv   = (const float*)d_in[6];
    float* out = (float*)d_out;
    char* ws = (char*)d_ws;

    size_t off_xx   = 0;                                   // bf16 [8192][512]  8 MB
    size_t off_qk   = off_xx   + (size_t)TT * CC * 2;      // bf16 [8192][128]  2 MB
    size_t off_wqkt = off_qk   + (size_t)TT * 128 * 2;     // bf16 [128][512]
    size_t off_wvt  = off_wqkt + (size_t)128 * 512 * 2;    // bf16 [512][512]
    size_t off_vt   = off_wvt  + (size_t)512 * 512 * 2;    // bf16 [512][8192]  8 MB

    // smallest CT with total blocks <= 512 (2 per CU, all resident)
    int CT = 2, slots = 0;
    for (;;) {
        slots = 0;
        for (int rt = 0; rt < 64; ++rt) slots += 4 * ((2 * rt + 2 + CT - 1) / CT);
        if (slots <= 512 || CT >= 256) break;
        ++CT;
    }

    u16* xx   = (u16*)(ws + off_xx);
    u16* qk   = (u16*)(ws + off_qk);
    u16* wqkt = (u16*)(ws + off_wqkt);
    u16* wvt  = (u16*)(ws + off_wvt);
    u16* vt   = (u16*)(ws + off_vt);

    const size_t flash_lds = (size_t)(8192 + 8192 + 16384) * sizeof(u16);  // 64 KB

    hipLaunchKernelGGL(lnw_kernel,     dim3(3328), dim3(256), 0, stream,
                       x, lns, lnb, Wq, Wk, Wv, xx, wqkt, wvt, out);
    hipLaunchKernelGGL(qk_gemm_kernel, dim3(256),  dim3(128), 0, stream, xx, wqkt, qk);
    hipLaunchKernelGGL(v_gemm_kernel,  dim3(512),  dim3(256), 0, stream, xe, wvt, vt);
    hipLaunchKernelGGL(flash_kernel,   dim3(slots), dim3(512), flash_lds, stream,
                       qk, vt, out, CT);
}

// Round 11
// 141.281 us; speedup vs baseline: 1.5772x; 1.0523x over previous
//
#include <hip/hip_runtime.h>

#define TT 8192
#define CC 512

typedef unsigned short u16;
typedef unsigned int u32;
typedef __attribute__((ext_vector_type(8))) short bf16x8;
typedef __attribute__((ext_vector_type(4))) float f32x4;

#define VMCNT0() asm volatile("s_waitcnt vmcnt(0)" ::: "memory")
#define LGKM0()  asm volatile("s_waitcnt lgkmcnt(0)" ::: "memory")

__device__ __forceinline__ u16 f2bf(float f) {          // RNE (cold paths)
    u32 u = __float_as_uint(f);
    return (u16)((u + 0x7FFFu + ((u >> 16) & 1u)) >> 16);
}
__device__ __forceinline__ u16 f2bf_fast(float f) {     // round-half-up (hot path)
    return (u16)((__float_as_uint(f) + 0x8000u) >> 16);
}

__device__ __forceinline__ void gld16(const u16* g, u16* l) {
    __builtin_amdgcn_global_load_lds(
        (const __attribute__((address_space(1))) u32*)g,
        (__attribute__((address_space(3))) u32*)l, 16, 0, 0);
}

// ---- Kernel 1: LN -> xx (bf16), out = x (residual pre-init), weight transposes ----
__global__ void lnw_kernel(const float* __restrict__ x,
                           const float* __restrict__ scale,
                           const float* __restrict__ bias,
                           const float* __restrict__ Wq,
                           const float* __restrict__ Wk,
                           const float* __restrict__ Wv,
                           u16* __restrict__ xx,
                           u16* __restrict__ wqkt,
                           u16* __restrict__ wvt,
                           float* __restrict__ out) {
    int b = blockIdx.x;
    if (b < 2048) {
        int row = b * 4 + (threadIdx.x >> 6);
        int l = threadIdx.x & 63;
        const float4* xr = (const float4*)(x + (size_t)row * CC);
        float4 a = xr[l * 2], c = xr[l * 2 + 1];
        float4* orow = (float4*)(out + (size_t)row * CC);
        orow[l * 2] = a;
        orow[l * 2 + 1] = c;
        float s = a.x + a.y + a.z + a.w + c.x + c.y + c.z + c.w;
        float q = a.x*a.x + a.y*a.y + a.z*a.z + a.w*a.w
                + c.x*c.x + c.y*c.y + c.z*c.z + c.w*c.w;
        #pragma unroll
        for (int m = 1; m < 64; m <<= 1) {
            s += __shfl_xor(s, m, 64);
            q += __shfl_xor(q, m, 64);
        }
        float mu = s * (1.0f / CC);
        float var = q * (1.0f / CC) - mu * mu;
        float rs = rsqrtf(var + 1e-5f);
        const float4* sc4 = (const float4*)scale;
        const float4* bi4 = (const float4*)bias;
        float4 s1 = sc4[l * 2], s2 = sc4[l * 2 + 1];
        float4 b1 = bi4[l * 2], b2 = bi4[l * 2 + 1];
        bf16x8 o;
        o[0] = (short)f2bf((a.x - mu) * rs * s1.x + b1.x);
        o[1] = (short)f2bf((a.y - mu) * rs * s1.y + b1.y);
        o[2] = (short)f2bf((a.z - mu) * rs * s1.z + b1.z);
        o[3] = (short)f2bf((a.w - mu) * rs * s1.w + b1.w);
        o[4] = (short)f2bf((c.x - mu) * rs * s2.x + b2.x);
        o[5] = (short)f2bf((c.y - mu) * rs * s2.y + b2.y);
        o[6] = (short)f2bf((c.z - mu) * rs * s2.z + b2.z);
        o[7] = (short)f2bf((c.w - mu) * rs * s2.w + b2.w);
        *(bf16x8*)(xx + (size_t)row * CC + l * 8) = o;
    } else {
        int tid = (b - 2048) * 256 + threadIdx.x;   // 0 .. 327679
        if (tid < 65536) {
            int c = tid >> 9, k = tid & 511;
            float w = (c < 64) ? Wq[k * 64 + c] : Wk[k * 64 + (c - 64)];
            wqkt[tid] = f2bf(w);
        } else {
            int i = tid - 65536;
            int c = i >> 9, k = i & 511;
            wvt[i] = f2bf(Wv[k * 512 + c]);
        }
    }
}

// ---------- Kernel 2 (fused): qk = xx @ [Wq|Wk] (blocks 0..127), vT = (xe @ Wv)^T (blocks 128..639) ----------
__global__ __launch_bounds__(256) void qkv_gemm_kernel(const u16* __restrict__ xx,
                                                       const u16* __restrict__ wqkt,
                                                       const float* __restrict__ xe,
                                                       const u16* __restrict__ wvt,
                                                       u16* __restrict__ qk,
                                                       u16* __restrict__ vt) {
    __shared__ u16 tl[128 * 72];
    int w = threadIdx.x >> 6;
    int l = threadIdx.x & 63;
    int l15 = l & 15, g = l >> 4;

    if (blockIdx.x < 128) {
        // qk part: 64 rows/block
        int r0 = blockIdx.x * 64 + w * 16;
        f32x4 acc[8];
        #pragma unroll
        for (int i = 0; i < 8; ++i) acc[i] = (f32x4){0.f, 0.f, 0.f, 0.f};
        for (int kk = 0; kk < 16; ++kk) {
            int k = kk * 32 + g * 8;
            bf16x8 af = *(const bf16x8*)(xx + (size_t)(r0 + l15) * CC + k);
            #pragma unroll
            for (int Nt = 0; Nt < 8; ++Nt) {
                int c = Nt * 16 + l15;
                bf16x8 bfr = *(const bf16x8*)(wqkt + c * CC + k);
                acc[Nt] = __builtin_amdgcn_mfma_f32_16x16x32_bf16(af, bfr, acc[Nt], 0, 0, 0);
            }
        }
        #pragma unroll
        for (int Nt = 0; Nt < 8; ++Nt) {
            int c = Nt * 16 + l15;
            float scl = (c < 64) ? 0.125f : 1.0f;
            #pragma unroll
            for (int jj = 0; jj < 4; ++jj) {
                int rg = r0 + g * 4 + jj;
                qk[rg * 128 + c] = f2bf(acc[Nt][jj] * scl);
            }
        }
    } else {
        // v part: 64 rows x 128 cols per block
        int b2 = blockIdx.x - 128;
        int bm = b2 >> 2, bn = b2 & 3;
        int r0 = bm * 64 + w * 16;
        int c0 = bn * 128;
        f32x4 acc[8];
        #pragma unroll
        for (int i = 0; i < 8; ++i) acc[i] = (f32x4){0.f, 0.f, 0.f, 0.f};
        for (int kk = 0; kk < 16; ++kk) {
            int k = kk * 32 + g * 8;
            const float4* ap = (const float4*)(xe + (size_t)(r0 + l15) * CC + k);
            float4 a1 = ap[0], a2 = ap[1];
            bf16x8 af;
            af[0] = (short)f2bf(a1.x); af[1] = (short)f2bf(a1.y);
            af[2] = (short)f2bf(a1.z); af[3] = (short)f2bf(a1.w);
            af[4] = (short)f2bf(a2.x); af[5] = (short)f2bf(a2.y);
            af[6] = (short)f2bf(a2.z); af[7] = (short)f2bf(a2.w);
            #pragma unroll
            for (int Nt = 0; Nt < 8; ++Nt) {
                int c = c0 + Nt * 16 + l15;
                bf16x8 bfr = *(const bf16x8*)(wvt + c * CC + k);
                acc[Nt] = __builtin_amdgcn_mfma_f32_16x16x32_bf16(af, bfr, acc[Nt], 0, 0, 0);
            }
        }
        #pragma unroll
        for (int Nt = 0; Nt < 8; ++Nt) {
            int c = Nt * 16 + l15;                 // local col 0..127
            #pragma unroll
            for (int jj = 0; jj < 4; ++jj) {
                int r = w * 16 + g * 4 + jj;       // local row 0..63
                tl[c * 72 + r] = f2bf(acc[Nt][jj]);
            }
        }
        __syncthreads();
        int rb = bm * 64;
        #pragma unroll
        for (int i = 0; i < 4; ++i) {
            int chunk = i * 256 + threadIdx.x;     // 0..1023
            int c = chunk >> 3, r8 = chunk & 7;
            bf16x8 o = *(const bf16x8*)&tl[c * 72 + r8 * 8];
            *(bf16x8*)(vt + (size_t)(c0 + c) * TT + rb + r8 * 8) = o;
        }
    }
}

// ---------- Kernel 3: flash, BM=128 x BN=128, 8 waves, 64KB LDS (2 blocks/CU) ----------
// K/V DMA double-buffered (global_load_lds, issue-after-barrier, full-iter span);
// j-loop unrolled x2 (static buffer parity); mask only on diagonal visits.
__global__ __launch_bounds__(512, 4) void flash_kernel(const u16* __restrict__ qk,
                                                       const u16* __restrict__ vt,
                                                       float* __restrict__ out,
                                                       int CT) {
    extern __shared__ u16 smem[];
    u16* const Klds = smem;            // 2 x [64 s][64 a] swizzled, 16KB
    u16* const Slds = smem + 8192;     // [128 r][64 s] swizzled, 16KB
    u16* const Vlds = smem + 16384;    // 2 x [128 c][64 s] swizzled, 32KB

    const int tid = threadIdx.x;
    const int w = tid >> 6, l = tid & 63;
    const int l15 = l & 15, g = l >> 4;
    const int wr = w >> 2, wcol = w & 3;     // PV: rows wr*64, cols wcol*32

    // decode blockIdx -> (rt, cb 0..3, ch); big-rt-first
    int b2 = (int)gridDim.x - 1 - (int)blockIdx.x;
    int rt = 0, base = 0;
    for (;;) {
        int nt_ = 2 * rt + 2, nc_ = (nt_ + CT - 1) / CT;
        if (b2 < base + 4 * nc_) break;
        base += 4 * nc_; ++rt;
    }
    const int rem = b2 - base;
    const int cb = rem & 3;
    const int ch = rem >> 2;
    const int nt = 2 * rt + 2, nc = (nt + CT - 1) / CT;
    const int t_lo = ch * nt / nc, t_hi = (ch + 1) * nt / nc;

    // Q fragments: wave w owns S rows [w*16, +16), pre-scaled by 1/8
    const int qrow = rt * 128 + w * 16 + l15;
    const bf16x8 qs0 = *(const bf16x8*)(qk + (size_t)qrow * 128 + g * 8);
    const bf16x8 qs1 = *(const bf16x8*)(qk + (size_t)qrow * 128 + 32 + g * 8);

    f32x4 acc[4][2];
    #pragma unroll
    for (int m = 0; m < 4; ++m)
        #pragma unroll
        for (int n = 0; n < 2; ++n) acc[m][n] = (f32x4){0.f, 0.f, 0.f, 0.f};

    // K DMA: 1 gld16/thread, linear dst, pre-swizzled source
    const int sIk = tid >> 3, pk = tid & 7;
    const int ka8 = (pk ^ (sIk & 7)) << 3;
    // V DMA: 2 gld16/thread
    const int vr = w * 8 + (l >> 3);
    const int vsw = ((l & 7) ^ (l >> 3)) << 3;

    #define K_DMA(JT, B) gld16(qk + (size_t)((JT) * 64 + sIk) * 128 + 64 + ka8, \
                               Klds + (B) * 4096 + sIk * 64 + pk * 8)
    #define V_DMA(JT, B) { \
        _Pragma("unroll") \
        for (int i = 0; i < 2; ++i) { \
            int c = i * 64 + vr; \
            gld16(vt + (size_t)(cb * 128 + c) * TT + (JT) * 64 + vsw, \
                  Vlds + (B) * 8192 + c * 64 + (l & 7) * 8); \
        } }

    // one flash iteration; CUR is a literal so all LDS addressing is static
    #define FLASH_ITER(J, CUR, MORE) { \
        VMCNT0(); \
        LGKM0(); \
        __builtin_amdgcn_s_barrier(); \
        if (MORE) { V_DMA((J) + 1, (CUR) ^ 1); K_DMA((J) + 1, (CUR) ^ 1); } \
        const u16* Kb = Klds + (CUR) * 4096; \
        f32x4 sacc[4]; \
        _Pragma("unroll") \
        for (int Nt = 0; Nt < 4; ++Nt) sacc[Nt] = (f32x4){0.f, 0.f, 0.f, 0.f}; \
        __builtin_amdgcn_s_setprio(1); \
        _Pragma("unroll") \
        for (int Nt = 0; Nt < 4; ++Nt) { \
            int srow = Nt * 16 + l15; \
            _Pragma("unroll") \
            for (int ka = 0; ka < 2; ++ka) { \
                int sl = (ka * 4 + g) ^ (srow & 7); \
                bf16x8 kf = *(const bf16x8*)&Kb[srow * 64 + sl * 8]; \
                sacc[Nt] = __builtin_amdgcn_mfma_f32_16x16x32_bf16( \
                    ka ? qs1 : qs0, kf, sacc[Nt], 0, 0, 0); \
            } \
        } \
        __builtin_amdgcn_s_setprio(0); \
        if ((J) >= 2 * rt) { \
            _Pragma("unroll") \
            for (int Nt = 0; Nt < 4; ++Nt) { \
                int scol = Nt * 16 + l15; \
                _Pragma("unroll") \
                for (int jj = 0; jj < 4; ++jj) { \
                    int row = w * 16 + g * 4 + jj; \
                    float val = sacc[Nt][jj]; \
                    if (((J) * 64 + scol) > rt * 128 + row) val = 0.f; \
                    Slds[row * 64 + ((((scol >> 3) ^ (row & 7)) << 3) + (scol & 7))] = f2bf_fast(val); \
                } \
            } \
        } else { \
            _Pragma("unroll") \
            for (int Nt = 0; Nt < 4; ++Nt) { \
                int scol = Nt * 16 + l15; \
                _Pragma("unroll") \
                for (int jj = 0; jj < 4; ++jj) { \
                    int row = w * 16 + g * 4 + jj; \
                    Slds[row * 64 + ((((scol >> 3) ^ (row & 7)) << 3) + (scol & 7))] = f2bf_fast(sacc[Nt][jj]); \
                } \
            } \
        } \
        LGKM0(); \
        __builtin_amdgcn_s_barrier(); \
        const u16* Vb = Vlds + (CUR) * 8192; \
        __builtin_amdgcn_s_setprio(1); \
        _Pragma("unroll") \
        for (int ka = 0; ka < 2; ++ka) { \
            bf16x8 sf[4], vf[2]; \
            _Pragma("unroll") \
            for (int Mt = 0; Mt < 4; ++Mt) { \
                int row = wr * 64 + Mt * 16 + l15; \
                int sl = (ka * 4 + g) ^ (row & 7); \
                sf[Mt] = *(const bf16x8*)&Slds[row * 64 + sl * 8]; \
            } \
            _Pragma("unroll") \
            for (int Nt = 0; Nt < 2; ++Nt) { \
                int cv = wcol * 32 + Nt * 16 + l15; \
                int ph = (ka * 4 + g) ^ (cv & 7); \
                vf[Nt] = *(const bf16x8*)&Vb[cv * 64 + ph * 8]; \
            } \
            _Pragma("unroll") \
            for (int Nt = 0; Nt < 2; ++Nt) \
                _Pragma("unroll") \
                for (int Mt = 0; Mt < 4; ++Mt) \
                    acc[Mt][Nt] = __builtin_amdgcn_mfma_f32_16x16x32_bf16( \
                        sf[Mt], vf[Nt], acc[Mt][Nt], 0, 0, 0); \
        } \
        __builtin_amdgcn_s_setprio(0); \
    }

    // prologue: DMA(t_lo) -> buf0
    V_DMA(t_lo, 0);
    K_DMA(t_lo, 0);

    // unrolled x2 main loop (static buffer parity), tail handles odd chunk length
    int j = t_lo;
    for (; j + 1 < t_hi; j += 2) {
        FLASH_ITER(j, 0, true);
        FLASH_ITER(j + 1, 1, (j + 2 < t_hi));
    }
    if (j < t_hi) FLASH_ITER(j, 0, false);

    // epilogue: nc==1 -> plain load+add+store (out pre-initialized to x); else atomic
    float* ob = out + (size_t)(rt * 128) * 512 + cb * 128;
    if (nc == 1) {
        #pragma unroll
        for (int Mt = 0; Mt < 4; ++Mt) {
            #pragma unroll
            for (int Nt = 0; Nt < 2; ++Nt) {
                int col = wcol * 32 + Nt * 16 + l15;
                #pragma unroll
                for (int jj = 0; jj < 4; ++jj) {
                    int row = wr * 64 + Mt * 16 + g * 4 + jj;
                    float* p = &ob[(size_t)row * 512 + col];
                    *p = *p + acc[Mt][Nt][jj];
                }
            }
        }
    } else {
        #pragma unroll
        for (int Mt = 0; Mt < 4; ++Mt) {
            #pragma unroll
            for (int Nt = 0; Nt < 2; ++Nt) {
                int col = wcol * 32 + Nt * 16 + l15;
                #pragma unroll
                for (int jj = 0; jj < 4; ++jj) {
                    int row = wr * 64 + Mt * 16 + g * 4 + jj;
                    atomicAdd(&ob[(size_t)row * 512 + col], acc[Mt][Nt][jj]);
                }
            }
        }
    }
    #undef K_DMA
    #undef V_DMA
    #undef FLASH_ITER
}

extern "C" void kernel_launch(void* const* d_in, const int* in_sizes, int n_in,
                              void* d_out, int out_size, void* d_ws, size_t ws_size,
                              hipStream_t stream) {
    (void)in_sizes; (void)n_in; (void)out_size; (void)ws_size;
    const float* x    = (const float*)d_in[0];
    const float* xe   = (const float*)d_in[1];
    const float* lns  = (const float*)d_in[2];
    const float* lnb  = (const float*)d_in[3];
    const float* Wq   = (const float*)d_in[4];
    const float* Wk   = (const float*)d_in[5];
    const float* Wv   = (const float*)d_in[6];
    float* out = (float*)d_out;
    char* ws = (char*)d_ws;

    size_t off_xx   = 0;                                   // bf16 [8192][512]  8 MB
    size_t off_qk   = off_xx   + (size_t)TT * CC * 2;      // bf16 [8192][128]  2 MB
    size_t off_wqkt = off_qk   + (size_t)TT * 128 * 2;     // bf16 [128][512]
    size_t off_wvt  = off_wqkt + (size_t)128 * 512 * 2;    // bf16 [512][512]
    size_t off_vt   = off_wvt  + (size_t)512 * 512 * 2;    // bf16 [512][8192]  8 MB

    // smallest CT with total blocks <= 512 (2 per CU, all resident)
    int CT = 2, slots = 0;
    for (;;) {
        slots = 0;
        for (int rt = 0; rt < 64; ++rt) slots += 4 * ((2 * rt + 2 + CT - 1) / CT);
        if (slots <= 512 || CT >= 256) break;
        ++CT;
    }

    u16* xx   = (u16*)(ws + off_xx);
    u16* qk   = (u16*)(ws + off_qk);
    u16* wqkt = (u16*)(ws + off_wqkt);
    u16* wvt  = (u16*)(ws + off_wvt);
    u16* vt   = (u16*)(ws + off_vt);

    const size_t flash_lds = (size_t)(8192 + 8192 + 16384) * sizeof(u16);  // 64 KB

    hipLaunchKernelGGL(lnw_kernel,      dim3(3328), dim3(256), 0, stream,
                       x, lns, lnb, Wq, Wk, Wv, xx, wqkt, wvt, out);
    hipLaunchKernelGGL(qkv_gemm_kernel, dim3(640),  dim3(256), 0, stream,
                       xx, wqkt, xe, wvt, qk, vt);
    hipLaunchKernelGGL(flash_kernel,    dim3(slots), dim3(512), flash_lds, stream,
                       qk, vt, out, CT);
}